// Round 1
// baseline (76.702 us; speedup 1.0000x reference)
//
#include <hip/hip_runtime.h>
#include <math.h>

// Problem constants (match reference)
#define BB   256
#define KK   16
#define NBIN 128
#define GG   (NBIN * NBIN)     // 16384 bins per batch
#define NT   1024              // threads per block
#define SPT  (GG / NT)         // 16 bins per thread

#if __has_builtin(__builtin_amdgcn_exp2f)
  #define EXP2F(x) __builtin_amdgcn_exp2f(x)
#else
  #define EXP2F(x) exp2f(x)
#endif

// One block per batch. Thread t owns bins g = s*1024 + t (s=0..15):
//   j = g & 127  (constant per thread)  -> dv fixed per (thread,k)
//   i = 8*s + (t>>7)                    -> du varies over s
// Coalesced stores: for fixed s, consecutive tids hit consecutive addresses.
__global__ __launch_bounds__(NT) void gmm_hist_kernel(
    const float* __restrict__ mu,     // [B,K,2]
    const float* __restrict__ sigma,  // [B,K,2]
    const float* __restrict__ cov12,  // [B,K]
    const float* __restrict__ pi_,    // [B,K]
    float* __restrict__ out)          // [B,128,128]
{
    const int b   = blockIdx.x;
    const int tid = threadIdx.x;

    __shared__ float s_mu_u[KK], s_mu_v[KK], s_ia[KK], s_ib2[KK], s_ic[KK], s_coef[KK];
    __shared__ float s_wsum[NT / 64];
    __shared__ float s_total;

    // ---- per-mixture precompute (threads 0..15), mirrors reference exactly ----
    if (tid < KK) {
        const int idx = b * KK + tid;
        const float m_u = mu[idx * 2 + 0];
        const float m_v = mu[idx * 2 + 1];
        const float su  = fmaxf(sigma[idx * 2 + 0], 0.001f);
        const float sv  = fmaxf(sigma[idx * 2 + 1], 0.001f);
        const float su2 = su * su;
        const float sv2 = sv * sv;
        const float c11 = su2 + 1e-6f;
        const float c22 = sv2 + 1e-6f;
        const float off = cov12[idx];
        const float det_full = c11 * c22 - off * off;
        const bool  valid    = (det_full > 0.0f);   // NaN compares false -> fallback, like ref
        const float det_safe = valid ? det_full : 1.0f;
        const float ia  = valid ? (c22 / det_safe) : (1.0f / su2);
        const float ib  = valid ? (-off / det_safe) : 0.0f;
        const float ic  = valid ? (c11 / det_safe) : (1.0f / sv2);
        const float det = valid ? det_full : (su2 * sv2);
        const float coef = pi_[idx] / (6.283185307179586f * sqrtf(det + 1e-6f));
        const float cs = -0.7213475204444817f;      // -0.5 * log2(e), folded into exponent
        s_mu_u[tid] = m_u;
        s_mu_v[tid] = m_v;
        s_ia[tid]   = ia * cs;
        s_ib2[tid]  = (2.0f * ib) * cs;
        s_ic[tid]   = ic * cs;
        s_coef[tid] = coef;
    }
    __syncthreads();

    const float step = 4.0f / 127.0f;               // linspace(-2,2,128) step
    const int   j    = tid & (NBIN - 1);
    const int   i0   = tid >> 7;                    // 0..7
    const float gv   = -2.0f + (float)j * step;

    // Row coordinates for this thread's 16 bins (exact per-bin formula, no drift)
    float u_s[SPT];
    #pragma unroll
    for (int s = 0; s < SPT; ++s)
        u_s[s] = -2.0f + (float)(i0 + 8 * s) * step;

    float acc[SPT];
    #pragma unroll
    for (int s = 0; s < SPT; ++s) acc[s] = 0.0f;

    // ---- main accumulation: 16 mixtures x 16 bins per thread ----
    #pragma unroll
    for (int k = 0; k < KK; ++k) {
        const float muu  = s_mu_u[k];
        const float dv   = gv - s_mu_v[k];
        const float ia   = s_ia[k];                 // pre-scaled by -0.5*log2e
        const float Bp   = s_ib2[k] * dv;
        const float Ap   = s_ic[k] * (dv * dv);
        const float coef = s_coef[k];
        #pragma unroll
        for (int s = 0; s < SPT; ++s) {
            const float du = u_s[s] - muu;                  // v_sub
            const float t  = __builtin_fmaf(ia, du, Bp);    // v_fma
            const float m  = __builtin_fmaf(du, t, Ap);     // v_fma  (m <= 0 always)
            const float e  = EXP2F(m);                      // v_exp_f32
            acc[s] = __builtin_fmaf(coef, e, acc[s]);       // v_fma
        }
    }

    // ---- block-wide sum for per-batch normalization ----
    float local = 0.0f;
    #pragma unroll
    for (int s = 0; s < SPT; ++s) local += acc[s];

    #pragma unroll
    for (int off = 32; off >= 1; off >>= 1)
        local += __shfl_down(local, off, 64);

    const int wave = tid >> 6;
    const int lane = tid & 63;
    if (lane == 0) s_wsum[wave] = local;
    __syncthreads();

    if (tid == 0) {
        float t = 0.0f;
        #pragma unroll
        for (int w = 0; w < NT / 64; ++w) t += s_wsum[w];
        s_total = (t > 0.0f) ? t : 1.0f;                    // ref: where(s>0, s, 1)
    }
    __syncthreads();

    const float inv = 1.0f / s_total;
    float* outb = out + (size_t)b * GG;
    #pragma unroll
    for (int s = 0; s < SPT; ++s)
        outb[s * NT + tid] = acc[s] * inv;                  // coalesced dword stores
}

extern "C" void kernel_launch(void* const* d_in, const int* in_sizes, int n_in,
                              void* d_out, int out_size, void* d_ws, size_t ws_size,
                              hipStream_t stream) {
    const float* mu    = (const float*)d_in[0];
    const float* sigma = (const float*)d_in[1];
    const float* cov12 = (const float*)d_in[2];
    const float* pi_   = (const float*)d_in[3];
    float* out = (float*)d_out;

    hipLaunchKernelGGL(gmm_hist_kernel, dim3(BB), dim3(NT), 0, stream,
                       mu, sigma, cov12, pi_, out);
}